// Round 1
// 776.379 us; speedup vs baseline: 3.3957x; 3.3957x over previous
//
#include <hip/hip_runtime.h>
#include <stdint.h>

#define NUM_TOKENS 8192
#define D_MODEL    2048
#define H_EXP      1408
#define NUM_EXP    8
#define TOPK       2
#define N_SLOTS    (NUM_TOKENS * TOPK)   // 16384
#define CAP        (N_SLOTS / NUM_EXP)   // 2048

typedef __attribute__((ext_vector_type(4))) float f32x4;
typedef __attribute__((ext_vector_type(8))) short short8_t;

__device__ __forceinline__ unsigned short f2bf(float f) {
    unsigned u = __float_as_uint(f);
    u += 0x7FFFu + ((u >> 16) & 1u);   // round-to-nearest-even
    return (unsigned short)(u >> 16);
}
__device__ __forceinline__ float bf2f(unsigned short h) {
    return __uint_as_float(((unsigned)h) << 16);
}
__device__ __forceinline__ void async_ld16(const void* g, void* l) {
    __builtin_amdgcn_global_load_lds(
        (const __attribute__((address_space(1))) void*)g,
        (__attribute__((address_space(3))) void*)l,
        16, 0, 0);
}

// ---------------------------------------------------------------------------
// 1) Routing: stable counting sort of slots by expert id.
//    Block e scans all slots; rank = #earlier slots with same expert.
// ---------------------------------------------------------------------------
__global__ void route_kernel(const int* __restrict__ topk_idx,
                             const float* __restrict__ topk_scr,
                             int* __restrict__ src_token,
                             float* __restrict__ src_score,
                             int* __restrict__ pos_of_slot) {
    const int e = blockIdx.x;
    const int tid = threadIdx.x;           // 0..255
    const int lane = tid & 63;
    const int wv = tid >> 6;               // 0..3
    __shared__ int wave_tot[4];
    __shared__ int base_s;
    if (tid == 0) base_s = 0;
    __syncthreads();
    for (int t0 = 0; t0 < N_SLOTS; t0 += 256) {
        const int s = t0 + tid;
        const bool m = (topk_idx[s] == e);
        const unsigned long long bal = __ballot(m);
        const int prefix = __popcll(bal & ((1ull << lane) - 1ull));
        if (lane == 0) wave_tot[wv] = __popcll(bal);
        __syncthreads();
        int wbase = 0;
        #pragma unroll
        for (int w = 0; w < 4; ++w) if (w < wv) wbase += wave_tot[w];
        const int btot = wave_tot[0] + wave_tot[1] + wave_tot[2] + wave_tot[3];
        if (m) {
            const int p = e * CAP + base_s + wbase + prefix;
            src_token[p] = s >> 1;          // slot / TOPK
            src_score[p] = topk_scr[s];
            pos_of_slot[s] = p;
        }
        __syncthreads();
        if (tid == 0) base_s += btot;
        __syncthreads();
    }
}

// ---------------------------------------------------------------------------
// 2) Weight fp32 -> bf16 with transpose:  in [R][C] -> out [C][R]
//    (so GEMM B operand is [N][K]: contiguous along K, same staging as A)
// ---------------------------------------------------------------------------
__global__ void transpose_cast_kernel(const float* __restrict__ in,
                                      unsigned short* __restrict__ out,
                                      int R, int C) {
    __shared__ float tile[32][33];
    const int c0 = blockIdx.x * 32;
    const int r0 = blockIdx.y * 32;
    const float* inp = in + (size_t)blockIdx.z * R * C;
    unsigned short* outp = out + (size_t)blockIdx.z * R * C;
    const int lr = threadIdx.x >> 3;        // 0..31
    const int lc = (threadIdx.x & 7) * 4;   // 0,4,...,28
    const float4 v = *(const float4*)(inp + (size_t)(r0 + lr) * C + c0 + lc);
    tile[lr][lc + 0] = v.x;
    tile[lr][lc + 1] = v.y;
    tile[lr][lc + 2] = v.z;
    tile[lr][lc + 3] = v.w;
    __syncthreads();
    ushort4 o;
    o.x = f2bf(tile[lc + 0][lr]);
    o.y = f2bf(tile[lc + 1][lr]);
    o.z = f2bf(tile[lc + 2][lr]);
    o.w = f2bf(tile[lc + 3][lr]);
    *(ushort4*)(outp + (size_t)(c0 + lr) * R + r0 + lc) = o;
}

// ---------------------------------------------------------------------------
// 3) Gather tokens into expert-sorted order, cast to bf16.
// ---------------------------------------------------------------------------
__global__ void gather_cast_kernel(const float* __restrict__ x,
                                   const int* __restrict__ src_token,
                                   unsigned short* __restrict__ xs) {
    const int p = blockIdx.x;
    const int t = src_token[p];
    const float4* src = (const float4*)(x + (size_t)t * D_MODEL);
    ushort4* dst = (ushort4*)(xs + (size_t)p * D_MODEL);
    for (int i = threadIdx.x; i < D_MODEL / 4; i += 256) {
        const float4 v = src[i];
        ushort4 o;
        o.x = f2bf(v.x); o.y = f2bf(v.y); o.z = f2bf(v.z); o.w = f2bf(v.w);
        dst[i] = o;
    }
}

// ---------------------------------------------------------------------------
// 4) Fused gate+up GEMM:  g = xs@Wg, u = xs@Wu, h = silu(g)*u   (per expert)
//    128x128 tile per B-matrix, BK=32, 16x16x32 bf16 MFMA, m97-style staging.
//    __launch_bounds__(256, 2): 256-thread block, min 2 waves/SIMD ->
//    register cap 256/thread (vs default 1024-thread cap of 128, which
//    spilled ~100 accumulator regs to scratch: 5.9 GB of HBM writes/dispatch).
// ---------------------------------------------------------------------------
__global__ void __launch_bounds__(256, 2)
gemm12_kernel(const unsigned short* __restrict__ xs,
              const unsigned short* __restrict__ Wgt,
              const unsigned short* __restrict__ Wut,
              unsigned short* __restrict__ hbuf) {
    __shared__ unsigned short As[128 * 32];
    __shared__ unsigned short Bgs[128 * 32];
    __shared__ unsigned short Bus[128 * 32];

    const int tid = threadIdx.x;
    const int lane = tid & 63;
    const int wv = tid >> 6;
    const int wm = wv & 1;
    const int wn = wv >> 1;
    const int quad = lane >> 4;
    const int l15 = lane & 15;

    const int mt = blockIdx.x;
    const int nt = blockIdx.y;
    const int e  = blockIdx.z;

    const size_t arow0 = (size_t)e * CAP + (size_t)mt * 128;
    const unsigned short* Ag  = xs + arow0 * D_MODEL;
    const unsigned short* Bgg = Wgt + ((size_t)e * H_EXP + (size_t)nt * 128) * D_MODEL;
    const unsigned short* Bug = Wut + ((size_t)e * H_EXP + (size_t)nt * 128) * D_MODEL;

    const int s1 = tid, s2 = tid + 256;
    const int r1 = s1 >> 2, c1 = (s1 & 3) * 8;
    const int r2 = s2 >> 2, c2 = (s2 & 3) * 8;

    const f32x4 zero4 = {0.0f, 0.0f, 0.0f, 0.0f};
    f32x4 accg[4][4], accu[4][4];
    #pragma unroll
    for (int i = 0; i < 4; i++)
        #pragma unroll
        for (int j = 0; j < 4; j++) { accg[i][j] = zero4; accu[i][j] = zero4; }

    for (int k0 = 0; k0 < D_MODEL; k0 += 32) {
        async_ld16(Ag  + (size_t)r1 * D_MODEL + k0 + c1, As  + s1 * 8);
        async_ld16(Ag  + (size_t)r2 * D_MODEL + k0 + c2, As  + s2 * 8);
        async_ld16(Bgg + (size_t)r1 * D_MODEL + k0 + c1, Bgs + s1 * 8);
        async_ld16(Bgg + (size_t)r2 * D_MODEL + k0 + c2, Bgs + s2 * 8);
        async_ld16(Bug + (size_t)r1 * D_MODEL + k0 + c1, Bus + s1 * 8);
        async_ld16(Bug + (size_t)r2 * D_MODEL + k0 + c2, Bus + s2 * 8);
        __syncthreads();

        short8_t af[4], bg[4], bu[4];
        #pragma unroll
        for (int mi = 0; mi < 4; mi++)
            af[mi] = *(const short8_t*)(As + (wm * 64 + mi * 16 + l15) * 32 + quad * 8);
        #pragma unroll
        for (int ni = 0; ni < 4; ni++) {
            bg[ni] = *(const short8_t*)(Bgs + (wn * 64 + ni * 16 + l15) * 32 + quad * 8);
            bu[ni] = *(const short8_t*)(Bus + (wn * 64 + ni * 16 + l15) * 32 + quad * 8);
        }
        #pragma unroll
        for (int mi = 0; mi < 4; mi++)
            #pragma unroll
            for (int ni = 0; ni < 4; ni++) {
                accg[mi][ni] = __builtin_amdgcn_mfma_f32_16x16x32_bf16(af[mi], bg[ni], accg[mi][ni], 0, 0, 0);
                accu[mi][ni] = __builtin_amdgcn_mfma_f32_16x16x32_bf16(af[mi], bu[ni], accu[mi][ni], 0, 0, 0);
            }
        __syncthreads();
    }

    // epilogue: h = silu(g) * u, bf16 store
    #pragma unroll
    for (int mi = 0; mi < 4; mi++) {
        #pragma unroll
        for (int r = 0; r < 4; r++) {
            const size_t grow = arow0 + (size_t)(wm * 64 + mi * 16 + quad * 4 + r);
            unsigned short* dst = hbuf + grow * H_EXP + (size_t)nt * 128 + wn * 64 + l15;
            #pragma unroll
            for (int ni = 0; ni < 4; ni++) {
                const float g = accg[mi][ni][r];
                const float u = accu[mi][ni][r];
                const float h = (g * u) / (1.0f + __expf(-g));
                dst[ni * 16] = f2bf(h);
            }
        }
    }
}

// ---------------------------------------------------------------------------
// 5) Down GEMM:  d = h @ Wd, scaled by per-row gate score  (per expert)
//    Same __launch_bounds__ rationale as gemm12.
// ---------------------------------------------------------------------------
__global__ void __launch_bounds__(256, 2)
gemm3_kernel(const unsigned short* __restrict__ hbuf,
             const unsigned short* __restrict__ Wdt,
             const float* __restrict__ src_score,
             unsigned short* __restrict__ dbuf) {
    __shared__ unsigned short As[128 * 32];
    __shared__ unsigned short Bs[128 * 32];

    const int tid = threadIdx.x;
    const int lane = tid & 63;
    const int wv = tid >> 6;
    const int wm = wv & 1;
    const int wn = wv >> 1;
    const int quad = lane >> 4;
    const int l15 = lane & 15;

    const int mt = blockIdx.x;
    const int nt = blockIdx.y;
    const int e  = blockIdx.z;

    const size_t arow0 = (size_t)e * CAP + (size_t)mt * 128;
    const unsigned short* Ag = hbuf + arow0 * H_EXP;
    const unsigned short* Bg = Wdt + ((size_t)e * D_MODEL + (size_t)nt * 128) * H_EXP;

    const int s1 = tid, s2 = tid + 256;
    const int r1 = s1 >> 2, c1 = (s1 & 3) * 8;
    const int r2 = s2 >> 2, c2 = (s2 & 3) * 8;

    const f32x4 zero4 = {0.0f, 0.0f, 0.0f, 0.0f};
    f32x4 acc[4][4];
    #pragma unroll
    for (int i = 0; i < 4; i++)
        #pragma unroll
        for (int j = 0; j < 4; j++) acc[i][j] = zero4;

    for (int k0 = 0; k0 < H_EXP; k0 += 32) {
        async_ld16(Ag + (size_t)r1 * H_EXP + k0 + c1, As + s1 * 8);
        async_ld16(Ag + (size_t)r2 * H_EXP + k0 + c2, As + s2 * 8);
        async_ld16(Bg + (size_t)r1 * H_EXP + k0 + c1, Bs + s1 * 8);
        async_ld16(Bg + (size_t)r2 * H_EXP + k0 + c2, Bs + s2 * 8);
        __syncthreads();

        short8_t af[4], bf[4];
        #pragma unroll
        for (int mi = 0; mi < 4; mi++)
            af[mi] = *(const short8_t*)(As + (wm * 64 + mi * 16 + l15) * 32 + quad * 8);
        #pragma unroll
        for (int ni = 0; ni < 4; ni++)
            bf[ni] = *(const short8_t*)(Bs + (wn * 64 + ni * 16 + l15) * 32 + quad * 8);
        #pragma unroll
        for (int mi = 0; mi < 4; mi++)
            #pragma unroll
            for (int ni = 0; ni < 4; ni++)
                acc[mi][ni] = __builtin_amdgcn_mfma_f32_16x16x32_bf16(af[mi], bf[ni], acc[mi][ni], 0, 0, 0);
        __syncthreads();
    }

    #pragma unroll
    for (int mi = 0; mi < 4; mi++) {
        #pragma unroll
        for (int r = 0; r < 4; r++) {
            const size_t grow = arow0 + (size_t)(wm * 64 + mi * 16 + quad * 4 + r);
            const float sc = src_score[grow];  // SCORE_SCALE_FACTOR = 1.0
            unsigned short* dst = dbuf + grow * D_MODEL + (size_t)nt * 128 + wn * 64 + l15;
            #pragma unroll
            for (int ni = 0; ni < 4; ni++)
                dst[ni * 16] = f2bf(acc[mi][ni][r] * sc);
        }
    }
}

// ---------------------------------------------------------------------------
// 6) Combine: y[t] = dbuf[pos[2t]] + dbuf[pos[2t+1]]   (deterministic)
// ---------------------------------------------------------------------------
__global__ void combine_kernel(const unsigned short* __restrict__ dbuf,
                               const int* __restrict__ pos_of_slot,
                               float* __restrict__ y) {
    const int t = blockIdx.x;
    const int p0 = pos_of_slot[2 * t];
    const int p1 = pos_of_slot[2 * t + 1];
    const ushort4* a = (const ushort4*)(dbuf + (size_t)p0 * D_MODEL);
    const ushort4* b = (const ushort4*)(dbuf + (size_t)p1 * D_MODEL);
    float4* o = (float4*)(y + (size_t)t * D_MODEL);
    for (int i = threadIdx.x; i < D_MODEL / 4; i += 256) {
        const ushort4 ua = a[i];
        const ushort4 ub = b[i];
        float4 v;
        v.x = bf2f(ua.x) + bf2f(ub.x);
        v.y = bf2f(ua.y) + bf2f(ub.y);
        v.z = bf2f(ua.z) + bf2f(ub.z);
        v.w = bf2f(ua.w) + bf2f(ub.w);
        o[i] = v;
    }
}

// ---------------------------------------------------------------------------
// Workspace layout (peak 205.7 MB):
//   buf0: Wgt during gemm12, then Wdt for gemm3   (46.1 MB)
//   buf1: Wut                                      (46.1 MB)
//   hb:   gate/up output                           (46.1 MB)
//   xs:   gathered bf16 tokens, then dbuf          (67.1 MB)
//   maps: src_token / src_score / pos_of_slot      (0.2 MB)
// ---------------------------------------------------------------------------
extern "C" void kernel_launch(void* const* d_in, const int* in_sizes, int n_in,
                              void* d_out, int out_size, void* d_ws, size_t ws_size,
                              hipStream_t stream) {
    const float* x        = (const float*)d_in[0];
    const int*   topk_idx = (const int*)d_in[1];
    const float* topk_scr = (const float*)d_in[2];
    const float* Wg       = (const float*)d_in[3];
    const float* Wu       = (const float*)d_in[4];
    const float* Wd       = (const float*)d_in[5];
    float* y = (float*)d_out;

    char* ws = (char*)d_ws;
    const size_t wbytes = (size_t)NUM_EXP * D_MODEL * H_EXP * 2;  // 46,137,344
    size_t off = 0;
    unsigned short* buf0 = (unsigned short*)(ws + off); off += wbytes;  // Wgt -> Wdt
    unsigned short* Wut  = (unsigned short*)(ws + off); off += wbytes;
    unsigned short* hb   = (unsigned short*)(ws + off); off += wbytes;
    unsigned short* xs   = (unsigned short*)(ws + off); off += (size_t)N_SLOTS * D_MODEL * 2;
    int*   src_token = (int*)(ws + off);   off += (size_t)N_SLOTS * 4;
    float* src_score = (float*)(ws + off); off += (size_t)N_SLOTS * 4;
    int*   pos_slot  = (int*)(ws + off);   off += (size_t)N_SLOTS * 4;
    unsigned short* Wgt  = buf0;
    unsigned short* Wdt  = buf0;  // reused after gemm12 (stream-serialized)
    unsigned short* dbuf = xs;    // xs dead after gemm12

    route_kernel<<<NUM_EXP, 256, 0, stream>>>(topk_idx, topk_scr, src_token, src_score, pos_slot);
    transpose_cast_kernel<<<dim3(H_EXP / 32, D_MODEL / 32, NUM_EXP), 256, 0, stream>>>(Wg, Wgt, D_MODEL, H_EXP);
    transpose_cast_kernel<<<dim3(H_EXP / 32, D_MODEL / 32, NUM_EXP), 256, 0, stream>>>(Wu, Wut, D_MODEL, H_EXP);
    gather_cast_kernel<<<N_SLOTS, 256, 0, stream>>>(x, src_token, xs);
    gemm12_kernel<<<dim3(CAP / 128, H_EXP / 128, NUM_EXP), 256, 0, stream>>>(xs, Wgt, Wut, hb);
    transpose_cast_kernel<<<dim3(D_MODEL / 32, H_EXP / 32, NUM_EXP), 256, 0, stream>>>(Wd, Wdt, H_EXP, D_MODEL);
    gemm3_kernel<<<dim3(CAP / 128, D_MODEL / 128, NUM_EXP), 256, 0, stream>>>(hb, Wdt, src_score, dbuf);
    combine_kernel<<<NUM_TOKENS, 256, 0, stream>>>(dbuf, pos_slot, y);
}

// Round 2
// 761.126 us; speedup vs baseline: 3.4637x; 1.0200x over previous
//
#include <hip/hip_runtime.h>
#include <stdint.h>

#define NUM_TOKENS 8192
#define D_MODEL    2048
#define H_EXP      1408
#define NUM_EXP    8
#define TOPK       2
#define N_SLOTS    (NUM_TOKENS * TOPK)   // 16384
#define CAP        (N_SLOTS / NUM_EXP)   // 2048

typedef __attribute__((ext_vector_type(4))) float f32x4;
typedef __attribute__((ext_vector_type(8))) short short8_t;

__device__ __forceinline__ unsigned short f2bf(float f) {
    unsigned u = __float_as_uint(f);
    u += 0x7FFFu + ((u >> 16) & 1u);   // round-to-nearest-even
    return (unsigned short)(u >> 16);
}
__device__ __forceinline__ float bf2f(unsigned short h) {
    return __uint_as_float(((unsigned)h) << 16);
}
__device__ __forceinline__ void async_ld16(const void* g, void* l) {
    __builtin_amdgcn_global_load_lds(
        (const __attribute__((address_space(1))) void*)g,
        (__attribute__((address_space(3))) void*)l,
        16, 0, 0);
}

// ---------------------------------------------------------------------------
// 1) Routing: stable counting sort of slots by expert id.
// ---------------------------------------------------------------------------
__global__ void route_kernel(const int* __restrict__ topk_idx,
                             const float* __restrict__ topk_scr,
                             int* __restrict__ src_token,
                             float* __restrict__ src_score,
                             int* __restrict__ pos_of_slot) {
    const int e = blockIdx.x;
    const int tid = threadIdx.x;           // 0..255
    const int lane = tid & 63;
    const int wv = tid >> 6;               // 0..3
    __shared__ int wave_tot[4];
    __shared__ int base_s;
    if (tid == 0) base_s = 0;
    __syncthreads();
    for (int t0 = 0; t0 < N_SLOTS; t0 += 256) {
        const int s = t0 + tid;
        const bool m = (topk_idx[s] == e);
        const unsigned long long bal = __ballot(m);
        const int prefix = __popcll(bal & ((1ull << lane) - 1ull));
        if (lane == 0) wave_tot[wv] = __popcll(bal);
        __syncthreads();
        int wbase = 0;
        #pragma unroll
        for (int w = 0; w < 4; ++w) if (w < wv) wbase += wave_tot[w];
        const int btot = wave_tot[0] + wave_tot[1] + wave_tot[2] + wave_tot[3];
        if (m) {
            const int p = e * CAP + base_s + wbase + prefix;
            src_token[p] = s >> 1;          // slot / TOPK
            src_score[p] = topk_scr[s];
            pos_of_slot[s] = p;
        }
        __syncthreads();
        if (tid == 0) base_s += btot;
        __syncthreads();
    }
}

// ---------------------------------------------------------------------------
// 2) Weight fp32 -> bf16 with transpose:  in [R][C] -> out [C][R]
// ---------------------------------------------------------------------------
__global__ void transpose_cast_kernel(const float* __restrict__ in,
                                      unsigned short* __restrict__ out,
                                      int R, int C) {
    __shared__ float tile[32][33];
    const int c0 = blockIdx.x * 32;
    const int r0 = blockIdx.y * 32;
    const float* inp = in + (size_t)blockIdx.z * R * C;
    unsigned short* outp = out + (size_t)blockIdx.z * R * C;
    const int lr = threadIdx.x >> 3;        // 0..31
    const int lc = (threadIdx.x & 7) * 4;   // 0,4,...,28
    const float4 v = *(const float4*)(inp + (size_t)(r0 + lr) * C + c0 + lc);
    tile[lr][lc + 0] = v.x;
    tile[lr][lc + 1] = v.y;
    tile[lr][lc + 2] = v.z;
    tile[lr][lc + 3] = v.w;
    __syncthreads();
    ushort4 o;
    o.x = f2bf(tile[lc + 0][lr]);
    o.y = f2bf(tile[lc + 1][lr]);
    o.z = f2bf(tile[lc + 2][lr]);
    o.w = f2bf(tile[lc + 3][lr]);
    *(ushort4*)(outp + (size_t)(c0 + lr) * R + r0 + lc) = o;
}

// ---------------------------------------------------------------------------
// 3) Gather tokens into expert-sorted order, cast to bf16.
// ---------------------------------------------------------------------------
__global__ void gather_cast_kernel(const float* __restrict__ x,
                                   const int* __restrict__ src_token,
                                   unsigned short* __restrict__ xs) {
    const int p = blockIdx.x;
    const int t = src_token[p];
    const float4* src = (const float4*)(x + (size_t)t * D_MODEL);
    ushort4* dst = (ushort4*)(xs + (size_t)p * D_MODEL);
    for (int i = threadIdx.x; i < D_MODEL / 4; i += 256) {
        const float4 v = src[i];
        ushort4 o;
        o.x = f2bf(v.x); o.y = f2bf(v.y); o.z = f2bf(v.z); o.w = f2bf(v.w);
        dst[i] = o;
    }
}

// ---------------------------------------------------------------------------
// 4) Fused gate+up GEMM:  g = xs@Wg, u = xs@Wu, h = silu(g)*u   (per expert)
//    Block tile 128(M) x 64(N), BK=32, 4 waves in 2Mx2N grid, per-wave
//    64x32 of BOTH g and u -> acc = 16 f32x4 = 64 regs (was 128).
//    With ~104 VGPR total budget ~168 <= 170 = 512/3 -> 3 waves/SIMD
//    (was 2 at 232 regs; m132 shows the 2-vs-3 occupancy cliff is ~1.7x).
//    MFMA:ds_read:gload per wave-K-step = 16:8:4 (m97's verified ratio).
// ---------------------------------------------------------------------------
__global__ void __launch_bounds__(256, 3)
gemm12_kernel(const unsigned short* __restrict__ xs,
              const unsigned short* __restrict__ Wgt,
              const unsigned short* __restrict__ Wut,
              unsigned short* __restrict__ hbuf) {
    __shared__ unsigned short As[128 * 32];   // 8 KB
    __shared__ unsigned short Bgs[64 * 32];   // 4 KB
    __shared__ unsigned short Bus[64 * 32];   // 4 KB

    const int tid = threadIdx.x;
    const int lane = tid & 63;
    const int wv = tid >> 6;
    const int wm = wv & 1;       // 2 wave-rows of 64
    const int wn = wv >> 1;      // 2 wave-cols of 32
    const int quad = lane >> 4;
    const int l15 = lane & 15;

    const int mt = blockIdx.x;
    const int nt = blockIdx.y;   // 0..21 (64-wide N tiles)
    const int e  = blockIdx.z;

    const size_t arow0 = (size_t)e * CAP + (size_t)mt * 128;
    const unsigned short* Ag  = xs + arow0 * D_MODEL;
    const unsigned short* Bgg = Wgt + ((size_t)e * H_EXP + (size_t)nt * 64) * D_MODEL;
    const unsigned short* Bug = Wut + ((size_t)e * H_EXP + (size_t)nt * 64) * D_MODEL;

    // A staging: two 16B loads/thread covering 128 rows x 32 cols
    const int s1 = tid, s2 = tid + 256;
    const int r1 = s1 >> 2, c1 = (s1 & 3) * 8;
    const int r2 = s2 >> 2, c2 = (s2 & 3) * 8;
    // B staging: one 16B load/thread per matrix covering 64 rows x 32 cols
    const int rb = tid >> 2, cb = (tid & 3) * 8;

    const f32x4 zero4 = {0.0f, 0.0f, 0.0f, 0.0f};
    f32x4 accg[4][2], accu[4][2];
    #pragma unroll
    for (int i = 0; i < 4; i++)
        #pragma unroll
        for (int j = 0; j < 2; j++) { accg[i][j] = zero4; accu[i][j] = zero4; }

    for (int k0 = 0; k0 < D_MODEL; k0 += 32) {
        async_ld16(Ag  + (size_t)r1 * D_MODEL + k0 + c1, As  + s1 * 8);
        async_ld16(Ag  + (size_t)r2 * D_MODEL + k0 + c2, As  + s2 * 8);
        async_ld16(Bgg + (size_t)rb * D_MODEL + k0 + cb, Bgs + tid * 8);
        async_ld16(Bug + (size_t)rb * D_MODEL + k0 + cb, Bus + tid * 8);
        __syncthreads();

        short8_t af[4], bg[2], bu[2];
        #pragma unroll
        for (int mi = 0; mi < 4; mi++)
            af[mi] = *(const short8_t*)(As + (wm * 64 + mi * 16 + l15) * 32 + quad * 8);
        #pragma unroll
        for (int ni = 0; ni < 2; ni++) {
            bg[ni] = *(const short8_t*)(Bgs + (wn * 32 + ni * 16 + l15) * 32 + quad * 8);
            bu[ni] = *(const short8_t*)(Bus + (wn * 32 + ni * 16 + l15) * 32 + quad * 8);
        }
        #pragma unroll
        for (int mi = 0; mi < 4; mi++)
            #pragma unroll
            for (int ni = 0; ni < 2; ni++) {
                accg[mi][ni] = __builtin_amdgcn_mfma_f32_16x16x32_bf16(af[mi], bg[ni], accg[mi][ni], 0, 0, 0);
                accu[mi][ni] = __builtin_amdgcn_mfma_f32_16x16x32_bf16(af[mi], bu[ni], accu[mi][ni], 0, 0, 0);
            }
        __syncthreads();
    }

    // epilogue: h = silu(g) * u, bf16 store
    #pragma unroll
    for (int mi = 0; mi < 4; mi++) {
        #pragma unroll
        for (int r = 0; r < 4; r++) {
            const size_t grow = arow0 + (size_t)(wm * 64 + mi * 16 + quad * 4 + r);
            unsigned short* dst = hbuf + grow * H_EXP + (size_t)nt * 64 + wn * 32 + l15;
            #pragma unroll
            for (int ni = 0; ni < 2; ni++) {
                const float g = accg[mi][ni][r];
                const float u = accu[mi][ni][r];
                const float h = (g * u) / (1.0f + __expf(-g));
                dst[ni * 16] = f2bf(h);
            }
        }
    }
}

// ---------------------------------------------------------------------------
// 5) Down GEMM:  d = h @ Wd, scaled by per-row gate score  (per expert)
//    acc = 64 regs + ~104 VGPR = ~168 <= 170 -> request 3 waves/SIMD.
// ---------------------------------------------------------------------------
__global__ void __launch_bounds__(256, 3)
gemm3_kernel(const unsigned short* __restrict__ hbuf,
             const unsigned short* __restrict__ Wdt,
             const float* __restrict__ src_score,
             unsigned short* __restrict__ dbuf) {
    __shared__ unsigned short As[128 * 32];
    __shared__ unsigned short Bs[128 * 32];

    const int tid = threadIdx.x;
    const int lane = tid & 63;
    const int wv = tid >> 6;
    const int wm = wv & 1;
    const int wn = wv >> 1;
    const int quad = lane >> 4;
    const int l15 = lane & 15;

    const int mt = blockIdx.x;
    const int nt = blockIdx.y;
    const int e  = blockIdx.z;

    const size_t arow0 = (size_t)e * CAP + (size_t)mt * 128;
    const unsigned short* Ag = hbuf + arow0 * H_EXP;
    const unsigned short* Bg = Wdt + ((size_t)e * D_MODEL + (size_t)nt * 128) * H_EXP;

    const int s1 = tid, s2 = tid + 256;
    const int r1 = s1 >> 2, c1 = (s1 & 3) * 8;
    const int r2 = s2 >> 2, c2 = (s2 & 3) * 8;

    const f32x4 zero4 = {0.0f, 0.0f, 0.0f, 0.0f};
    f32x4 acc[4][4];
    #pragma unroll
    for (int i = 0; i < 4; i++)
        #pragma unroll
        for (int j = 0; j < 4; j++) acc[i][j] = zero4;

    for (int k0 = 0; k0 < H_EXP; k0 += 32) {
        async_ld16(Ag + (size_t)r1 * H_EXP + k0 + c1, As + s1 * 8);
        async_ld16(Ag + (size_t)r2 * H_EXP + k0 + c2, As + s2 * 8);
        async_ld16(Bg + (size_t)r1 * H_EXP + k0 + c1, Bs + s1 * 8);
        async_ld16(Bg + (size_t)r2 * H_EXP + k0 + c2, Bs + s2 * 8);
        __syncthreads();

        short8_t af[4], bf[4];
        #pragma unroll
        for (int mi = 0; mi < 4; mi++)
            af[mi] = *(const short8_t*)(As + (wm * 64 + mi * 16 + l15) * 32 + quad * 8);
        #pragma unroll
        for (int ni = 0; ni < 4; ni++)
            bf[ni] = *(const short8_t*)(Bs + (wn * 64 + ni * 16 + l15) * 32 + quad * 8);
        #pragma unroll
        for (int mi = 0; mi < 4; mi++)
            #pragma unroll
            for (int ni = 0; ni < 4; ni++)
                acc[mi][ni] = __builtin_amdgcn_mfma_f32_16x16x32_bf16(af[mi], bf[ni], acc[mi][ni], 0, 0, 0);
        __syncthreads();
    }

    #pragma unroll
    for (int mi = 0; mi < 4; mi++) {
        #pragma unroll
        for (int r = 0; r < 4; r++) {
            const size_t grow = arow0 + (size_t)(wm * 64 + mi * 16 + quad * 4 + r);
            const float sc = src_score[grow];  // SCORE_SCALE_FACTOR = 1.0
            unsigned short* dst = dbuf + grow * D_MODEL + (size_t)nt * 128 + wn * 64 + l15;
            #pragma unroll
            for (int ni = 0; ni < 4; ni++)
                dst[ni * 16] = f2bf(acc[mi][ni][r] * sc);
        }
    }
}

// ---------------------------------------------------------------------------
// 6) Combine: y[t] = dbuf[pos[2t]] + dbuf[pos[2t+1]]   (deterministic)
// ---------------------------------------------------------------------------
__global__ void combine_kernel(const unsigned short* __restrict__ dbuf,
                               const int* __restrict__ pos_of_slot,
                               float* __restrict__ y) {
    const int t = blockIdx.x;
    const int p0 = pos_of_slot[2 * t];
    const int p1 = pos_of_slot[2 * t + 1];
    const ushort4* a = (const ushort4*)(dbuf + (size_t)p0 * D_MODEL);
    const ushort4* b = (const ushort4*)(dbuf + (size_t)p1 * D_MODEL);
    float4* o = (float4*)(y + (size_t)t * D_MODEL);
    for (int i = threadIdx.x; i < D_MODEL / 4; i += 256) {
        const ushort4 ua = a[i];
        const ushort4 ub = b[i];
        float4 v;
        v.x = bf2f(ua.x) + bf2f(ub.x);
        v.y = bf2f(ua.y) + bf2f(ub.y);
        v.z = bf2f(ua.z) + bf2f(ub.z);
        v.w = bf2f(ua.w) + bf2f(ub.w);
        o[i] = v;
    }
}

// ---------------------------------------------------------------------------
// Workspace layout (peak 205.7 MB):
//   buf0: Wgt during gemm12, then Wdt for gemm3   (46.1 MB)
//   buf1: Wut                                      (46.1 MB)
//   hb:   gate/up output                           (46.1 MB)
//   xs:   gathered bf16 tokens, then dbuf          (67.1 MB)
//   maps: src_token / src_score / pos_of_slot      (0.2 MB)
// ---------------------------------------------------------------------------
extern "C" void kernel_launch(void* const* d_in, const int* in_sizes, int n_in,
                              void* d_out, int out_size, void* d_ws, size_t ws_size,
                              hipStream_t stream) {
    const float* x        = (const float*)d_in[0];
    const int*   topk_idx = (const int*)d_in[1];
    const float* topk_scr = (const float*)d_in[2];
    const float* Wg       = (const float*)d_in[3];
    const float* Wu       = (const float*)d_in[4];
    const float* Wd       = (const float*)d_in[5];
    float* y = (float*)d_out;

    char* ws = (char*)d_ws;
    const size_t wbytes = (size_t)NUM_EXP * D_MODEL * H_EXP * 2;  // 46,137,344
    size_t off = 0;
    unsigned short* buf0 = (unsigned short*)(ws + off); off += wbytes;  // Wgt -> Wdt
    unsigned short* Wut  = (unsigned short*)(ws + off); off += wbytes;
    unsigned short* hb   = (unsigned short*)(ws + off); off += wbytes;
    unsigned short* xs   = (unsigned short*)(ws + off); off += (size_t)N_SLOTS * D_MODEL * 2;
    int*   src_token = (int*)(ws + off);   off += (size_t)N_SLOTS * 4;
    float* src_score = (float*)(ws + off); off += (size_t)N_SLOTS * 4;
    int*   pos_slot  = (int*)(ws + off);   off += (size_t)N_SLOTS * 4;
    unsigned short* Wgt  = buf0;
    unsigned short* Wdt  = buf0;  // reused after gemm12 (stream-serialized)
    unsigned short* dbuf = xs;    // xs dead after gemm12

    route_kernel<<<NUM_EXP, 256, 0, stream>>>(topk_idx, topk_scr, src_token, src_score, pos_slot);
    transpose_cast_kernel<<<dim3(H_EXP / 32, D_MODEL / 32, NUM_EXP), 256, 0, stream>>>(Wg, Wgt, D_MODEL, H_EXP);
    transpose_cast_kernel<<<dim3(H_EXP / 32, D_MODEL / 32, NUM_EXP), 256, 0, stream>>>(Wu, Wut, D_MODEL, H_EXP);
    gather_cast_kernel<<<N_SLOTS, 256, 0, stream>>>(x, src_token, xs);
    gemm12_kernel<<<dim3(CAP / 128, H_EXP / 64, NUM_EXP), 256, 0, stream>>>(xs, Wgt, Wut, hb);
    transpose_cast_kernel<<<dim3(D_MODEL / 32, H_EXP / 32, NUM_EXP), 256, 0, stream>>>(Wd, Wdt, H_EXP, D_MODEL);
    gemm3_kernel<<<dim3(CAP / 128, D_MODEL / 128, NUM_EXP), 256, 0, stream>>>(hb, Wdt, src_score, dbuf);
    combine_kernel<<<NUM_TOKENS, 256, 0, stream>>>(dbuf, pos_slot, y);
}

// Round 3
// 718.833 us; speedup vs baseline: 3.6675x; 1.0588x over previous
//
#include <hip/hip_runtime.h>
#include <stdint.h>

#define NUM_TOKENS 8192
#define D_MODEL    2048
#define H_EXP      1408
#define NUM_EXP    8
#define TOPK       2
#define N_SLOTS    (NUM_TOKENS * TOPK)   // 16384
#define CAP        (N_SLOTS / NUM_EXP)   // 2048
#define KT12       (D_MODEL / 64)        // 32 K-tiles for gemm12

typedef __attribute__((ext_vector_type(4))) float f32x4;
typedef __attribute__((ext_vector_type(8))) short short8_t;

__device__ __forceinline__ unsigned short f2bf(float f) {
    unsigned u = __float_as_uint(f);
    u += 0x7FFFu + ((u >> 16) & 1u);   // round-to-nearest-even
    return (unsigned short)(u >> 16);
}
__device__ __forceinline__ float bf2f(unsigned short h) {
    return __uint_as_float(((unsigned)h) << 16);
}
__device__ __forceinline__ void async_ld16(const void* g, void* l) {
    __builtin_amdgcn_global_load_lds(
        (const __attribute__((address_space(1))) void*)g,
        (__attribute__((address_space(3))) void*)l,
        16, 0, 0);
}

// ---------------------------------------------------------------------------
// 1) Routing: stable counting sort of slots by expert id.
// ---------------------------------------------------------------------------
__global__ void route_kernel(const int* __restrict__ topk_idx,
                             const float* __restrict__ topk_scr,
                             int* __restrict__ src_token,
                             float* __restrict__ src_score,
                             int* __restrict__ pos_of_slot) {
    const int e = blockIdx.x;
    const int tid = threadIdx.x;           // 0..255
    const int lane = tid & 63;
    const int wv = tid >> 6;               // 0..3
    __shared__ int wave_tot[4];
    __shared__ int base_s;
    if (tid == 0) base_s = 0;
    __syncthreads();
    for (int t0 = 0; t0 < N_SLOTS; t0 += 256) {
        const int s = t0 + tid;
        const bool m = (topk_idx[s] == e);
        const unsigned long long bal = __ballot(m);
        const int prefix = __popcll(bal & ((1ull << lane) - 1ull));
        if (lane == 0) wave_tot[wv] = __popcll(bal);
        __syncthreads();
        int wbase = 0;
        #pragma unroll
        for (int w = 0; w < 4; ++w) if (w < wv) wbase += wave_tot[w];
        const int btot = wave_tot[0] + wave_tot[1] + wave_tot[2] + wave_tot[3];
        if (m) {
            const int p = e * CAP + base_s + wbase + prefix;
            src_token[p] = s >> 1;          // slot / TOPK
            src_score[p] = topk_scr[s];
            pos_of_slot[s] = p;
        }
        __syncthreads();
        if (tid == 0) base_s += btot;
        __syncthreads();
    }
}

// ---------------------------------------------------------------------------
// 2) Weight fp32 -> bf16 with transpose:  in [R][C] -> out [C][R]
// ---------------------------------------------------------------------------
__global__ void transpose_cast_kernel(const float* __restrict__ in,
                                      unsigned short* __restrict__ out,
                                      int R, int C) {
    __shared__ float tile[32][33];
    const int c0 = blockIdx.x * 32;
    const int r0 = blockIdx.y * 32;
    const float* inp = in + (size_t)blockIdx.z * R * C;
    unsigned short* outp = out + (size_t)blockIdx.z * R * C;
    const int lr = threadIdx.x >> 3;        // 0..31
    const int lc = (threadIdx.x & 7) * 4;   // 0,4,...,28
    const float4 v = *(const float4*)(inp + (size_t)(r0 + lr) * C + c0 + lc);
    tile[lr][lc + 0] = v.x;
    tile[lr][lc + 1] = v.y;
    tile[lr][lc + 2] = v.z;
    tile[lr][lc + 3] = v.w;
    __syncthreads();
    ushort4 o;
    o.x = f2bf(tile[lc + 0][lr]);
    o.y = f2bf(tile[lc + 1][lr]);
    o.z = f2bf(tile[lc + 2][lr]);
    o.w = f2bf(tile[lc + 3][lr]);
    *(ushort4*)(outp + (size_t)(c0 + lr) * R + r0 + lc) = o;
}

// ---------------------------------------------------------------------------
// 3) Gather tokens into expert-sorted order, cast to bf16.
// ---------------------------------------------------------------------------
__global__ void gather_cast_kernel(const float* __restrict__ x,
                                   const int* __restrict__ src_token,
                                   unsigned short* __restrict__ xs) {
    const int p = blockIdx.x;
    const int t = src_token[p];
    const float4* src = (const float4*)(x + (size_t)t * D_MODEL);
    ushort4* dst = (ushort4*)(xs + (size_t)p * D_MODEL);
    for (int i = threadIdx.x; i < D_MODEL / 4; i += 256) {
        const float4 v = src[i];
        ushort4 o;
        o.x = f2bf(v.x); o.y = f2bf(v.y); o.z = f2bf(v.z); o.w = f2bf(v.w);
        dst[i] = o;
    }
}

// ---------------------------------------------------------------------------
// 4) Fused gate+up GEMM, 8-phase schedule (T2+T3+T4+T5, m201 template):
//    BM=256, BN=128 (g AND u), BK=64, 512 thr = 8 waves (4M x 2N),
//    per-wave 64x64 of both g and u (acc = 128 VGPR).
//    LDS: 2 bufs x (A 32K + Bg 16K + Bu 16K) = 128 KiB, 1 block/CU.
//    Per K-tile: 4 phases x 16 MFMA; one 2-load stage unit per phase.
//    Counted vmcnt (never 0 in main loop): vmcnt(4)@P2-exit gates Bu(t),
//    vmcnt(2)@P4-exit gates A+Bg(t+1). LDS XOR-swizzle granule^=(row&7)
//    applied on SOURCE (global_load_lds dest must stay linear, rule #21)
//    and on ds_read -> 16-way bank conflict becomes 2-way (free).
// ---------------------------------------------------------------------------
#define STAGE_U(ldsbase, src, stride, k0)                                        \
    async_ld16((src) + (size_t)rA * (stride) + (k0) + gA * 8, (ldsbase) + tid * 8); \
    async_ld16((src) + (size_t)rB * (stride) + (k0) + gA * 8, (ldsbase) + (tid + 512) * 8);

#define READ_B(dstf, matoff, njbase)                                             \
    _Pragma("unroll")                                                            \
    for (int nj = 0; nj < 2; ++nj) {                                             \
        _Pragma("unroll")                                                        \
        for (int ks = 0; ks < 2; ++ks) {                                         \
            const int rr = brow + (njbase + nj) * 16;                            \
            dstf[nj][ks] = *(const short8_t*)(cb + (matoff) + rr * 64 +          \
                               (((ks * 4 + quad) ^ (rr & 7)) * 8));              \
        }                                                                        \
    }

#define MFMA_BLK(acc, bfr, njbase)                                               \
    _Pragma("unroll")                                                            \
    for (int mi = 0; mi < 4; ++mi) {                                             \
        _Pragma("unroll")                                                        \
        for (int nj = 0; nj < 2; ++nj) {                                         \
            _Pragma("unroll")                                                    \
            for (int ks = 0; ks < 2; ++ks)                                       \
                acc[mi][(njbase) + nj] = __builtin_amdgcn_mfma_f32_16x16x32_bf16( \
                    af[mi][ks], bfr[nj][ks], acc[mi][(njbase) + nj], 0, 0, 0);   \
        }                                                                        \
    }

#define BAR()    __builtin_amdgcn_s_barrier()
#define LGKM0()  do { asm volatile("s_waitcnt lgkmcnt(0)" ::: "memory");         \
                      __builtin_amdgcn_sched_barrier(0); } while (0)

__global__ void __launch_bounds__(512, 2)
gemm12_kernel(const unsigned short* __restrict__ xs,
              const unsigned short* __restrict__ Wgt,
              const unsigned short* __restrict__ Wut,
              unsigned short* __restrict__ hbuf) {
    // per buffer: A at 0 (256 rows x 64), Bg at 16384 shorts, Bu at 24576
    __shared__ unsigned short lds[2][512 * 64];   // 128 KiB

    const int tid  = threadIdx.x;          // 0..511
    const int lane = tid & 63;
    const int wv   = tid >> 6;             // 0..7
    const int wm   = wv & 3;               // 4 M-waves x 64 rows
    const int wn   = wv >> 2;              // 2 N-waves x 64 cols
    const int quad = lane >> 4;
    const int l15  = lane & 15;

    const int mt = blockIdx.x;             // 0..7
    const int nt = blockIdx.y;             // 0..10
    const int e  = blockIdx.z;

    const size_t arow0 = (size_t)e * CAP + (size_t)mt * 256;
    const unsigned short* Ag  = xs  + arow0 * D_MODEL;
    const unsigned short* Bgg = Wgt + ((size_t)e * H_EXP + (size_t)nt * 128) * D_MODEL;
    const unsigned short* Bug = Wut + ((size_t)e * H_EXP + (size_t)nt * 128) * D_MODEL;

    // staging: slot s covers (row = s>>3, 16B granule). Source granule is
    // pre-swizzled: g = (s&7) ^ (row&7); LDS dest linear (lane x 16B).
    const int rA = tid >> 3;               // rows 0..63   (slot tid)
    const int rB = rA + 64;                // rows 64..127 (slot tid+512); rB&7 == rA&7
    const int gA = (tid & 7) ^ (rA & 7);

    const int arow = wm * 64 + l15;
    const int brow = wn * 64 + l15;

    const f32x4 zero4 = {0.0f, 0.0f, 0.0f, 0.0f};
    f32x4 accg[4][4], accu[4][4];
    #pragma unroll
    for (int i = 0; i < 4; i++)
        #pragma unroll
        for (int j = 0; j < 4; j++) { accg[i][j] = zero4; accu[i][j] = zero4; }

    // prologue: stage K-tile 0 into buf 0 (order: A0, A1, Bg, Bu)
    {
        unsigned short* nb = &lds[0][0];
        STAGE_U(nb +     0, Ag,                         D_MODEL, 0);
        STAGE_U(nb +  8192, Ag + (size_t)128 * D_MODEL, D_MODEL, 0);
        STAGE_U(nb + 16384, Bgg,                        D_MODEL, 0);
        STAGE_U(nb + 24576, Bug,                        D_MODEL, 0);
    }
    asm volatile("s_waitcnt vmcnt(2)" ::: "memory");  // A0,A1,Bg done; Bu may fly
    BAR();

    for (int t = 0; t < KT12; ++t) {
        const unsigned short* cb = &lds[t & 1][0];
        unsigned short* nb = &lds[(t + 1) & 1][0];
        const int k1 = (t + 1) * 64;
        const bool st = (t + 1) < KT12;

        short8_t af[4][2], b2[2][2];

        // ---- P1: read A(all 8) + Bg nj0-1; stage A0(t+1); MFMA g nj0-1
        #pragma unroll
        for (int mi = 0; mi < 4; ++mi) {
            #pragma unroll
            for (int ks = 0; ks < 2; ++ks) {
                const int rr = arow + mi * 16;
                af[mi][ks] = *(const short8_t*)(cb + rr * 64 +
                                 (((ks * 4 + quad) ^ (rr & 7)) * 8));
            }
        }
        READ_B(b2, 16384, 0);
        if (st) { STAGE_U(nb + 0, Ag, D_MODEL, k1); }
        BAR(); LGKM0();
        __builtin_amdgcn_s_setprio(1);
        MFMA_BLK(accg, b2, 0);
        __builtin_amdgcn_s_setprio(0);
        BAR();

        // ---- P2: read Bg nj2-3; stage A1(t+1); MFMA g nj2-3; gate Bu(t)
        READ_B(b2, 16384, 2);
        if (st) { STAGE_U(nb + 8192, Ag + (size_t)128 * D_MODEL, D_MODEL, k1); }
        BAR(); LGKM0();
        __builtin_amdgcn_s_setprio(1);
        MFMA_BLK(accg, b2, 2);
        __builtin_amdgcn_s_setprio(0);
        if (st) asm volatile("s_waitcnt vmcnt(4)" ::: "memory");
        else    asm volatile("s_waitcnt vmcnt(0)" ::: "memory");
        BAR();

        // ---- P3: read Bu nj0-1; stage Bg(t+1); MFMA u nj0-1
        READ_B(b2, 24576, 0);
        if (st) { STAGE_U(nb + 16384, Bgg, D_MODEL, k1); }
        BAR(); LGKM0();
        __builtin_amdgcn_s_setprio(1);
        MFMA_BLK(accu, b2, 0);
        __builtin_amdgcn_s_setprio(0);
        BAR();

        // ---- P4: read Bu nj2-3; stage Bu(t+1); MFMA u nj2-3; gate A+Bg(t+1)
        READ_B(b2, 24576, 2);
        if (st) { STAGE_U(nb + 24576, Bug, D_MODEL, k1); }
        BAR(); LGKM0();
        __builtin_amdgcn_s_setprio(1);
        MFMA_BLK(accu, b2, 2);
        __builtin_amdgcn_s_setprio(0);
        asm volatile("s_waitcnt vmcnt(2)" ::: "memory");
        BAR();
    }

    // epilogue: h = silu(g) * u, bf16 store
    #pragma unroll
    for (int mi = 0; mi < 4; ++mi) {
        #pragma unroll
        for (int r = 0; r < 4; ++r) {
            const size_t grow = arow0 + (size_t)(wm * 64 + mi * 16 + quad * 4 + r);
            unsigned short* dst = hbuf + grow * H_EXP + (size_t)nt * 128 + wn * 64 + l15;
            #pragma unroll
            for (int nj = 0; nj < 4; ++nj) {
                const float g = accg[mi][nj][r];
                const float u = accu[mi][nj][r];
                const float h = (g * u) / (1.0f + __expf(-g));
                dst[nj * 16] = f2bf(h);
            }
        }
    }
}

// ---------------------------------------------------------------------------
// 5) Down GEMM:  d = h @ Wd, scaled by per-row gate score  (per expert)
//    (unchanged 2-phase this round for clean attribution of gemm12 delta)
// ---------------------------------------------------------------------------
__global__ void __launch_bounds__(256, 3)
gemm3_kernel(const unsigned short* __restrict__ hbuf,
             const unsigned short* __restrict__ Wdt,
             const float* __restrict__ src_score,
             unsigned short* __restrict__ dbuf) {
    __shared__ unsigned short As[128 * 32];
    __shared__ unsigned short Bs[128 * 32];

    const int tid = threadIdx.x;
    const int lane = tid & 63;
    const int wv = tid >> 6;
    const int wm = wv & 1;
    const int wn = wv >> 1;
    const int quad = lane >> 4;
    const int l15 = lane & 15;

    const int mt = blockIdx.x;
    const int nt = blockIdx.y;
    const int e  = blockIdx.z;

    const size_t arow0 = (size_t)e * CAP + (size_t)mt * 128;
    const unsigned short* Ag = hbuf + arow0 * H_EXP;
    const unsigned short* Bg = Wdt + ((size_t)e * D_MODEL + (size_t)nt * 128) * H_EXP;

    const int s1 = tid, s2 = tid + 256;
    const int r1 = s1 >> 2, c1 = (s1 & 3) * 8;
    const int r2 = s2 >> 2, c2 = (s2 & 3) * 8;

    const f32x4 zero4 = {0.0f, 0.0f, 0.0f, 0.0f};
    f32x4 acc[4][4];
    #pragma unroll
    for (int i = 0; i < 4; i++)
        #pragma unroll
        for (int j = 0; j < 4; j++) acc[i][j] = zero4;

    for (int k0 = 0; k0 < H_EXP; k0 += 32) {
        async_ld16(Ag + (size_t)r1 * H_EXP + k0 + c1, As + s1 * 8);
        async_ld16(Ag + (size_t)r2 * H_EXP + k0 + c2, As + s2 * 8);
        async_ld16(Bg + (size_t)r1 * H_EXP + k0 + c1, Bs + s1 * 8);
        async_ld16(Bg + (size_t)r2 * H_EXP + k0 + c2, Bs + s2 * 8);
        __syncthreads();

        short8_t af[4], bf[4];
        #pragma unroll
        for (int mi = 0; mi < 4; mi++)
            af[mi] = *(const short8_t*)(As + (wm * 64 + mi * 16 + l15) * 32 + quad * 8);
        #pragma unroll
        for (int ni = 0; ni < 4; ni++)
            bf[ni] = *(const short8_t*)(Bs + (wn * 64 + ni * 16 + l15) * 32 + quad * 8);
        #pragma unroll
        for (int mi = 0; mi < 4; mi++)
            #pragma unroll
            for (int ni = 0; ni < 4; ni++)
                acc[mi][ni] = __builtin_amdgcn_mfma_f32_16x16x32_bf16(af[mi], bf[ni], acc[mi][ni], 0, 0, 0);
        __syncthreads();
    }

    #pragma unroll
    for (int mi = 0; mi < 4; mi++) {
        #pragma unroll
        for (int r = 0; r < 4; r++) {
            const size_t grow = arow0 + (size_t)(wm * 64 + mi * 16 + quad * 4 + r);
            const float sc = src_score[grow];  // SCORE_SCALE_FACTOR = 1.0
            unsigned short* dst = dbuf + grow * D_MODEL + (size_t)nt * 128 + wn * 64 + l15;
            #pragma unroll
            for (int ni = 0; ni < 4; ni++)
                dst[ni * 16] = f2bf(acc[mi][ni][r] * sc);
        }
    }
}

// ---------------------------------------------------------------------------
// 6) Combine: y[t] = dbuf[pos[2t]] + dbuf[pos[2t+1]]   (deterministic)
// ---------------------------------------------------------------------------
__global__ void combine_kernel(const unsigned short* __restrict__ dbuf,
                               const int* __restrict__ pos_of_slot,
                               float* __restrict__ y) {
    const int t = blockIdx.x;
    const int p0 = pos_of_slot[2 * t];
    const int p1 = pos_of_slot[2 * t + 1];
    const ushort4* a = (const ushort4*)(dbuf + (size_t)p0 * D_MODEL);
    const ushort4* b = (const ushort4*)(dbuf + (size_t)p1 * D_MODEL);
    float4* o = (float4*)(y + (size_t)t * D_MODEL);
    for (int i = threadIdx.x; i < D_MODEL / 4; i += 256) {
        const ushort4 ua = a[i];
        const ushort4 ub = b[i];
        float4 v;
        v.x = bf2f(ua.x) + bf2f(ub.x);
        v.y = bf2f(ua.y) + bf2f(ub.y);
        v.z = bf2f(ua.z) + bf2f(ub.z);
        v.w = bf2f(ua.w) + bf2f(ub.w);
        o[i] = v;
    }
}

// ---------------------------------------------------------------------------
// Workspace layout (peak 205.7 MB)
// ---------------------------------------------------------------------------
extern "C" void kernel_launch(void* const* d_in, const int* in_sizes, int n_in,
                              void* d_out, int out_size, void* d_ws, size_t ws_size,
                              hipStream_t stream) {
    const float* x        = (const float*)d_in[0];
    const int*   topk_idx = (const int*)d_in[1];
    const float* topk_scr = (const float*)d_in[2];
    const float* Wg       = (const float*)d_in[3];
    const float* Wu       = (const float*)d_in[4];
    const float* Wd       = (const float*)d_in[5];
    float* y = (float*)d_out;

    char* ws = (char*)d_ws;
    const size_t wbytes = (size_t)NUM_EXP * D_MODEL * H_EXP * 2;  // 46,137,344
    size_t off = 0;
    unsigned short* buf0 = (unsigned short*)(ws + off); off += wbytes;  // Wgt -> Wdt
    unsigned short* Wut  = (unsigned short*)(ws + off); off += wbytes;
    unsigned short* hb   = (unsigned short*)(ws + off); off += wbytes;
    unsigned short* xs   = (unsigned short*)(ws + off); off += (size_t)N_SLOTS * D_MODEL * 2;
    int*   src_token = (int*)(ws + off);   off += (size_t)N_SLOTS * 4;
    float* src_score = (float*)(ws + off); off += (size_t)N_SLOTS * 4;
    int*   pos_slot  = (int*)(ws + off);   off += (size_t)N_SLOTS * 4;
    unsigned short* Wgt  = buf0;
    unsigned short* Wdt  = buf0;  // reused after gemm12 (stream-serialized)
    unsigned short* dbuf = xs;    // xs dead after gemm12

    route_kernel<<<NUM_EXP, 256, 0, stream>>>(topk_idx, topk_scr, src_token, src_score, pos_slot);
    transpose_cast_kernel<<<dim3(H_EXP / 32, D_MODEL / 32, NUM_EXP), 256, 0, stream>>>(Wg, Wgt, D_MODEL, H_EXP);
    transpose_cast_kernel<<<dim3(H_EXP / 32, D_MODEL / 32, NUM_EXP), 256, 0, stream>>>(Wu, Wut, D_MODEL, H_EXP);
    gather_cast_kernel<<<N_SLOTS, 256, 0, stream>>>(x, src_token, xs);
    gemm12_kernel<<<dim3(CAP / 256, H_EXP / 128, NUM_EXP), 512, 0, stream>>>(xs, Wgt, Wut, hb);
    transpose_cast_kernel<<<dim3(D_MODEL / 32, H_EXP / 32, NUM_EXP), 256, 0, stream>>>(Wd, Wdt, H_EXP, D_MODEL);
    gemm3_kernel<<<dim3(CAP / 128, D_MODEL / 128, NUM_EXP), 256, 0, stream>>>(hb, Wdt, src_score, dbuf);
    combine_kernel<<<NUM_TOKENS, 256, 0, stream>>>(dbuf, pos_slot, y);
}

// Round 4
// 684.825 us; speedup vs baseline: 3.8497x; 1.0497x over previous
//
#include <hip/hip_runtime.h>
#include <stdint.h>

#define NUM_TOKENS 8192
#define D_MODEL    2048
#define H_EXP      1408
#define NUM_EXP    8
#define TOPK       2
#define N_SLOTS    (NUM_TOKENS * TOPK)   // 16384
#define CAP        (N_SLOTS / NUM_EXP)   // 2048
#define KT12       (D_MODEL / 64)        // 32 K-tiles for gemm12
#define KT3        (H_EXP / 64)          // 22 K-tiles for gemm3

typedef __attribute__((ext_vector_type(4))) float f32x4;
typedef __attribute__((ext_vector_type(8))) short short8_t;

__device__ __forceinline__ unsigned short f2bf(float f) {
    unsigned u = __float_as_uint(f);
    u += 0x7FFFu + ((u >> 16) & 1u);   // round-to-nearest-even
    return (unsigned short)(u >> 16);
}
__device__ __forceinline__ float bf2f(unsigned short h) {
    return __uint_as_float(((unsigned)h) << 16);
}
__device__ __forceinline__ void async_ld16(const void* g, void* l) {
    __builtin_amdgcn_global_load_lds(
        (const __attribute__((address_space(1))) void*)g,
        (__attribute__((address_space(3))) void*)l,
        16, 0, 0);
}

// ---------------------------------------------------------------------------
// 1) Routing: stable counting sort of slots by expert id.
// ---------------------------------------------------------------------------
__global__ void route_kernel(const int* __restrict__ topk_idx,
                             const float* __restrict__ topk_scr,
                             int* __restrict__ src_token,
                             float* __restrict__ src_score,
                             int* __restrict__ pos_of_slot) {
    const int e = blockIdx.x;
    const int tid = threadIdx.x;           // 0..255
    const int lane = tid & 63;
    const int wv = tid >> 6;               // 0..3
    __shared__ int wave_tot[4];
    __shared__ int base_s;
    if (tid == 0) base_s = 0;
    __syncthreads();
    for (int t0 = 0; t0 < N_SLOTS; t0 += 256) {
        const int s = t0 + tid;
        const bool m = (topk_idx[s] == e);
        const unsigned long long bal = __ballot(m);
        const int prefix = __popcll(bal & ((1ull << lane) - 1ull));
        if (lane == 0) wave_tot[wv] = __popcll(bal);
        __syncthreads();
        int wbase = 0;
        #pragma unroll
        for (int w = 0; w < 4; ++w) if (w < wv) wbase += wave_tot[w];
        const int btot = wave_tot[0] + wave_tot[1] + wave_tot[2] + wave_tot[3];
        if (m) {
            const int p = e * CAP + base_s + wbase + prefix;
            src_token[p] = s >> 1;          // slot / TOPK
            src_score[p] = topk_scr[s];
            pos_of_slot[s] = p;
        }
        __syncthreads();
        if (tid == 0) base_s += btot;
        __syncthreads();
    }
}

// ---------------------------------------------------------------------------
// 2) Weight fp32 -> bf16 with transpose:  in [R][C] -> out [C][R]
// ---------------------------------------------------------------------------
__global__ void transpose_cast_kernel(const float* __restrict__ in,
                                      unsigned short* __restrict__ out,
                                      int R, int C) {
    __shared__ float tile[32][33];
    const int c0 = blockIdx.x * 32;
    const int r0 = blockIdx.y * 32;
    const float* inp = in + (size_t)blockIdx.z * R * C;
    unsigned short* outp = out + (size_t)blockIdx.z * R * C;
    const int lr = threadIdx.x >> 3;        // 0..31
    const int lc = (threadIdx.x & 7) * 4;   // 0,4,...,28
    const float4 v = *(const float4*)(inp + (size_t)(r0 + lr) * C + c0 + lc);
    tile[lr][lc + 0] = v.x;
    tile[lr][lc + 1] = v.y;
    tile[lr][lc + 2] = v.z;
    tile[lr][lc + 3] = v.w;
    __syncthreads();
    ushort4 o;
    o.x = f2bf(tile[lc + 0][lr]);
    o.y = f2bf(tile[lc + 1][lr]);
    o.z = f2bf(tile[lc + 2][lr]);
    o.w = f2bf(tile[lc + 3][lr]);
    *(ushort4*)(outp + (size_t)(c0 + lr) * R + r0 + lc) = o;
}

// ---------------------------------------------------------------------------
// 3) Gather tokens into expert-sorted order, cast to bf16.
// ---------------------------------------------------------------------------
__global__ void gather_cast_kernel(const float* __restrict__ x,
                                   const int* __restrict__ src_token,
                                   unsigned short* __restrict__ xs) {
    const int p = blockIdx.x;
    const int t = src_token[p];
    const float4* src = (const float4*)(x + (size_t)t * D_MODEL);
    ushort4* dst = (ushort4*)(xs + (size_t)p * D_MODEL);
    for (int i = threadIdx.x; i < D_MODEL / 4; i += 256) {
        const float4 v = src[i];
        ushort4 o;
        o.x = f2bf(v.x); o.y = f2bf(v.y); o.z = f2bf(v.z); o.w = f2bf(v.w);
        dst[i] = o;
    }
}

// ---------------------------------------------------------------------------
// Shared 8-phase machinery (m201 template; verified on gemm12 in R3:
// bank conflicts 2.3e7 -> 0, MfmaUtil 33 -> 43%, 1.33x).
// ---------------------------------------------------------------------------
#define STAGE_U(ldsbase, src, stride, k0)                                        \
    async_ld16((src) + (size_t)rA * (stride) + (k0) + gA * 8, (ldsbase) + tid * 8); \
    async_ld16((src) + (size_t)rB * (stride) + (k0) + gA * 8, (ldsbase) + (tid + 512) * 8);

#define READ_B(dstf, matoff, njbase)                                             \
    _Pragma("unroll")                                                            \
    for (int nj = 0; nj < 2; ++nj) {                                             \
        _Pragma("unroll")                                                        \
        for (int ks = 0; ks < 2; ++ks) {                                         \
            const int rr = brow + (njbase + nj) * 16;                            \
            dstf[nj][ks] = *(const short8_t*)(cb + (matoff) + rr * 64 +          \
                               (((ks * 4 + quad) ^ (rr & 7)) * 8));              \
        }                                                                        \
    }

// gemm3 B-read: rows span the full 256-row B region at LDS offset 16384.
// nj 0-3 -> B0 rows wn*64+nj*16 (phases P1/P2); nj 4-7 -> B1 rows
// 128+wn*64+(nj-4)*16 (P3/P4) -- keeps the vmcnt gate ordering identical
// to gemm12 (P2-exit gates B1(t), P4-exit gates A+B0(t+1)).
#define READ_B3(dstf, njbase)                                                    \
    {                                                                            \
        const int rbase = ((njbase) < 4 ? wn * 64 + (njbase) * 16                \
                                        : 128 + wn * 64 + ((njbase) - 4) * 16);  \
        _Pragma("unroll")                                                        \
        for (int nj = 0; nj < 2; ++nj) {                                         \
            _Pragma("unroll")                                                    \
            for (int ks = 0; ks < 2; ++ks) {                                     \
                const int rr = rbase + nj * 16 + l15;                            \
                dstf[nj][ks] = *(const short8_t*)(cb + 16384 + rr * 64 +         \
                                   (((ks * 4 + quad) ^ (rr & 7)) * 8));          \
            }                                                                    \
        }                                                                        \
    }

#define MFMA_BLK(acc, bfr, njbase)                                               \
    _Pragma("unroll")                                                            \
    for (int mi = 0; mi < 4; ++mi) {                                             \
        _Pragma("unroll")                                                        \
        for (int nj = 0; nj < 2; ++nj) {                                         \
            _Pragma("unroll")                                                    \
            for (int ks = 0; ks < 2; ++ks)                                       \
                acc[mi][(njbase) + nj] = __builtin_amdgcn_mfma_f32_16x16x32_bf16( \
                    af[mi][ks], bfr[nj][ks], acc[mi][(njbase) + nj], 0, 0, 0);   \
        }                                                                        \
    }

#define READ_A(cbuf)                                                             \
    _Pragma("unroll")                                                            \
    for (int mi = 0; mi < 4; ++mi) {                                             \
        _Pragma("unroll")                                                        \
        for (int ks = 0; ks < 2; ++ks) {                                         \
            const int rr = arow + mi * 16;                                       \
            af[mi][ks] = *(const short8_t*)((cbuf) + rr * 64 +                   \
                             (((ks * 4 + quad) ^ (rr & 7)) * 8));                \
        }                                                                        \
    }

#define BAR()    __builtin_amdgcn_s_barrier()
#define LGKM0()  do { asm volatile("s_waitcnt lgkmcnt(0)" ::: "memory");         \
                      __builtin_amdgcn_sched_barrier(0); } while (0)

// ---------------------------------------------------------------------------
// 4) Fused gate+up GEMM, 8-phase schedule (T2+T3+T4+T5):
//    BM=256, BN=128 (g AND u), BK=64, 512 thr = 8 waves (4M x 2N).
//    (unchanged from R3: 190 us, MfmaUtil 43%, bank-conflict 0)
// ---------------------------------------------------------------------------
__global__ void __launch_bounds__(512, 2)
gemm12_kernel(const unsigned short* __restrict__ xs,
              const unsigned short* __restrict__ Wgt,
              const unsigned short* __restrict__ Wut,
              unsigned short* __restrict__ hbuf) {
    // per buffer: A at 0 (256 rows x 64), Bg at 16384 shorts, Bu at 24576
    __shared__ unsigned short lds[2][512 * 64];   // 128 KiB

    const int tid  = threadIdx.x;          // 0..511
    const int lane = tid & 63;
    const int wv   = tid >> 6;             // 0..7
    const int wm   = wv & 3;               // 4 M-waves x 64 rows
    const int wn   = wv >> 2;              // 2 N-waves x 64 cols
    const int quad = lane >> 4;
    const int l15  = lane & 15;

    const int mt = blockIdx.x;             // 0..7
    const int nt = blockIdx.y;             // 0..10
    const int e  = blockIdx.z;

    const size_t arow0 = (size_t)e * CAP + (size_t)mt * 256;
    const unsigned short* Ag  = xs  + arow0 * D_MODEL;
    const unsigned short* Bgg = Wgt + ((size_t)e * H_EXP + (size_t)nt * 128) * D_MODEL;
    const unsigned short* Bug = Wut + ((size_t)e * H_EXP + (size_t)nt * 128) * D_MODEL;

    // staging: slot s covers (row = s>>3, 16B granule). Source granule is
    // pre-swizzled: g = (s&7) ^ (row&7); LDS dest linear (lane x 16B).
    const int rA = tid >> 3;               // rows 0..63   (slot tid)
    const int rB = rA + 64;                // rows 64..127 (slot tid+512)
    const int gA = (tid & 7) ^ (rA & 7);

    const int arow = wm * 64 + l15;
    const int brow = wn * 64 + l15;

    const f32x4 zero4 = {0.0f, 0.0f, 0.0f, 0.0f};
    f32x4 accg[4][4], accu[4][4];
    #pragma unroll
    for (int i = 0; i < 4; i++)
        #pragma unroll
        for (int j = 0; j < 4; j++) { accg[i][j] = zero4; accu[i][j] = zero4; }

    // prologue: stage K-tile 0 into buf 0 (order: A0, A1, Bg, Bu)
    {
        unsigned short* nb = &lds[0][0];
        STAGE_U(nb +     0, Ag,                         D_MODEL, 0);
        STAGE_U(nb +  8192, Ag + (size_t)128 * D_MODEL, D_MODEL, 0);
        STAGE_U(nb + 16384, Bgg,                        D_MODEL, 0);
        STAGE_U(nb + 24576, Bug,                        D_MODEL, 0);
    }
    asm volatile("s_waitcnt vmcnt(2)" ::: "memory");  // A0,A1,Bg done; Bu may fly
    BAR();

    for (int t = 0; t < KT12; ++t) {
        const unsigned short* cb = &lds[t & 1][0];
        unsigned short* nb = &lds[(t + 1) & 1][0];
        const int k1 = (t + 1) * 64;
        const bool st = (t + 1) < KT12;

        short8_t af[4][2], b2[2][2];

        // ---- P1: read A(all 8) + Bg nj0-1; stage A0(t+1); MFMA g nj0-1
        READ_A(cb);
        READ_B(b2, 16384, 0);
        if (st) { STAGE_U(nb + 0, Ag, D_MODEL, k1); }
        BAR(); LGKM0();
        __builtin_amdgcn_s_setprio(1);
        MFMA_BLK(accg, b2, 0);
        __builtin_amdgcn_s_setprio(0);
        BAR();

        // ---- P2: read Bg nj2-3; stage A1(t+1); MFMA g nj2-3; gate Bu(t)
        READ_B(b2, 16384, 2);
        if (st) { STAGE_U(nb + 8192, Ag + (size_t)128 * D_MODEL, D_MODEL, k1); }
        BAR(); LGKM0();
        __builtin_amdgcn_s_setprio(1);
        MFMA_BLK(accg, b2, 2);
        __builtin_amdgcn_s_setprio(0);
        if (st) asm volatile("s_waitcnt vmcnt(4)" ::: "memory");
        else    asm volatile("s_waitcnt vmcnt(0)" ::: "memory");
        BAR();

        // ---- P3: read Bu nj0-1; stage Bg(t+1); MFMA u nj0-1
        READ_B(b2, 24576, 0);
        if (st) { STAGE_U(nb + 16384, Bgg, D_MODEL, k1); }
        BAR(); LGKM0();
        __builtin_amdgcn_s_setprio(1);
        MFMA_BLK(accu, b2, 0);
        __builtin_amdgcn_s_setprio(0);
        BAR();

        // ---- P4: read Bu nj2-3; stage Bu(t+1); MFMA u nj2-3; gate A+Bg(t+1)
        READ_B(b2, 24576, 2);
        if (st) { STAGE_U(nb + 24576, Bug, D_MODEL, k1); }
        BAR(); LGKM0();
        __builtin_amdgcn_s_setprio(1);
        MFMA_BLK(accu, b2, 2);
        __builtin_amdgcn_s_setprio(0);
        asm volatile("s_waitcnt vmcnt(2)" ::: "memory");
        BAR();
    }

    // epilogue: h = silu(g) * u, bf16 store
    #pragma unroll
    for (int mi = 0; mi < 4; ++mi) {
        #pragma unroll
        for (int r = 0; r < 4; ++r) {
            const size_t grow = arow0 + (size_t)(wm * 64 + mi * 16 + quad * 4 + r);
            unsigned short* dst = hbuf + grow * H_EXP + (size_t)nt * 128 + wn * 64 + l15;
            #pragma unroll
            for (int nj = 0; nj < 4; ++nj) {
                const float g = accg[mi][nj][r];
                const float u = accu[mi][nj][r];
                const float h = (g * u) / (1.0f + __expf(-g));
                dst[nj * 16] = f2bf(h);
            }
        }
    }
}

// ---------------------------------------------------------------------------
// 5) Down GEMM, 8-phase schedule (same template as gemm12):
//    BM=256, BN=256, BK=64, 512 thr = 8 waves (4M x 2N), per-wave 64x128
//    -> acc[4][8] = 128 VGPR (same budget as gemm12's accg+accu).
//    LDS layout identical: A0 @0, A1 @8192, B0 @16384, B1 @24576 shorts
//    (B0/B1 contiguous -> B row r in [0,256) reads at 16384 + r*64).
//    Counted vmcnt: P2-exit vmcnt(4) gates B1(t) before P3 reads nj4-7;
//    P4-exit vmcnt(2) gates A+B0(t+1). K order matches old BK=32 loop
//    (ks 0 then 1) -> bitwise-identical accumulation.
// ---------------------------------------------------------------------------
__global__ void __launch_bounds__(512, 2)
gemm3_kernel(const unsigned short* __restrict__ hbuf,
             const unsigned short* __restrict__ Wdt,
             const float* __restrict__ src_score,
             unsigned short* __restrict__ dbuf) {
    __shared__ unsigned short lds[2][512 * 64];   // 128 KiB

    const int tid  = threadIdx.x;          // 0..511
    const int lane = tid & 63;
    const int wv   = tid >> 6;             // 0..7
    const int wm   = wv & 3;               // 4 M-waves x 64 rows
    const int wn   = wv >> 2;              // 2 N-waves x 128 cols (split halves)
    const int quad = lane >> 4;
    const int l15  = lane & 15;

    const int mt = blockIdx.x;             // 0..7
    const int nt = blockIdx.y;             // 0..7
    const int e  = blockIdx.z;

    const size_t arow0 = (size_t)e * CAP + (size_t)mt * 256;
    const unsigned short* Ag = hbuf + arow0 * H_EXP;
    const unsigned short* Bg = Wdt + ((size_t)e * D_MODEL + (size_t)nt * 256) * H_EXP;

    const int rA = tid >> 3;               // rows 0..63
    const int rB = rA + 64;                // rows 64..127
    const int gA = (tid & 7) ^ (rA & 7);

    const int arow = wm * 64 + l15;

    const f32x4 zero4 = {0.0f, 0.0f, 0.0f, 0.0f};
    f32x4 acc[4][8];
    #pragma unroll
    for (int i = 0; i < 4; i++)
        #pragma unroll
        for (int j = 0; j < 8; j++) acc[i][j] = zero4;

    // prologue: stage K-tile 0 (order: A0, A1, B0, B1)
    {
        unsigned short* nb = &lds[0][0];
        STAGE_U(nb +     0, Ag,                       H_EXP, 0);
        STAGE_U(nb +  8192, Ag + (size_t)128 * H_EXP, H_EXP, 0);
        STAGE_U(nb + 16384, Bg,                       H_EXP, 0);
        STAGE_U(nb + 24576, Bg + (size_t)128 * H_EXP, H_EXP, 0);
    }
    asm volatile("s_waitcnt vmcnt(2)" ::: "memory");  // A0,A1,B0 done; B1 may fly
    BAR();

    for (int t = 0; t < KT3; ++t) {
        const unsigned short* cb = &lds[t & 1][0];
        unsigned short* nb = &lds[(t + 1) & 1][0];
        const int k1 = (t + 1) * 64;
        const bool st = (t + 1) < KT3;

        short8_t af[4][2], b2[2][2];

        // ---- P1: read A(all 8) + B nj0-1 (B0); stage A0(t+1); MFMA nj0-1
        READ_A(cb);
        READ_B3(b2, 0);
        if (st) { STAGE_U(nb + 0, Ag, H_EXP, k1); }
        BAR(); LGKM0();
        __builtin_amdgcn_s_setprio(1);
        MFMA_BLK(acc, b2, 0);
        __builtin_amdgcn_s_setprio(0);
        BAR();

        // ---- P2: read B nj2-3 (B0); stage A1(t+1); MFMA nj2-3; gate B1(t)
        READ_B3(b2, 2);
        if (st) { STAGE_U(nb + 8192, Ag + (size_t)128 * H_EXP, H_EXP, k1); }
        BAR(); LGKM0();
        __builtin_amdgcn_s_setprio(1);
        MFMA_BLK(acc, b2, 2);
        __builtin_amdgcn_s_setprio(0);
        if (st) asm volatile("s_waitcnt vmcnt(4)" ::: "memory");
        else    asm volatile("s_waitcnt vmcnt(0)" ::: "memory");
        BAR();

        // ---- P3: read B nj4-5 (B1); stage B0(t+1); MFMA nj4-5
        READ_B3(b2, 4);
        if (st) { STAGE_U(nb + 16384, Bg, H_EXP, k1); }
        BAR(); LGKM0();
        __builtin_amdgcn_s_setprio(1);
        MFMA_BLK(acc, b2, 4);
        __builtin_amdgcn_s_setprio(0);
        BAR();

        // ---- P4: read B nj6-7 (B1); stage B1(t+1); MFMA nj6-7; gate A+B0(t+1)
        READ_B3(b2, 6);
        if (st) { STAGE_U(nb + 24576, Bg + (size_t)128 * H_EXP, H_EXP, k1); }
        BAR(); LGKM0();
        __builtin_amdgcn_s_setprio(1);
        MFMA_BLK(acc, b2, 6);
        __builtin_amdgcn_s_setprio(0);
        asm volatile("s_waitcnt vmcnt(2)" ::: "memory");
        BAR();
    }

    // epilogue: scale by gate score, bf16 store
    #pragma unroll
    for (int mi = 0; mi < 4; ++mi) {
        #pragma unroll
        for (int r = 0; r < 4; ++r) {
            const size_t grow = arow0 + (size_t)(wm * 64 + mi * 16 + quad * 4 + r);
            const float sc = src_score[grow];  // SCORE_SCALE_FACTOR = 1.0
            unsigned short* dst = dbuf + grow * D_MODEL + (size_t)nt * 256;
            #pragma unroll
            for (int nj = 0; nj < 8; ++nj) {
                const int col = (nj < 4 ? wn * 64 + nj * 16
                                        : 128 + wn * 64 + (nj - 4) * 16) + l15;
                dst[col] = f2bf(acc[mi][nj][r] * sc);
            }
        }
    }
}

// ---------------------------------------------------------------------------
// 6) Combine: y[t] = dbuf[pos[2t]] + dbuf[pos[2t+1]]   (deterministic)
// ---------------------------------------------------------------------------
__global__ void combine_kernel(const unsigned short* __restrict__ dbuf,
                               const int* __restrict__ pos_of_slot,
                               float* __restrict__ y) {
    const int t = blockIdx.x;
    const int p0 = pos_of_slot[2 * t];
    const int p1 = pos_of_slot[2 * t + 1];
    const ushort4* a = (const ushort4*)(dbuf + (size_t)p0 * D_MODEL);
    const ushort4* b = (const ushort4*)(dbuf + (size_t)p1 * D_MODEL);
    float4* o = (float4*)(y + (size_t)t * D_MODEL);
    for (int i = threadIdx.x; i < D_MODEL / 4; i += 256) {
        const ushort4 ua = a[i];
        const ushort4 ub = b[i];
        float4 v;
        v.x = bf2f(ua.x) + bf2f(ub.x);
        v.y = bf2f(ua.y) + bf2f(ub.y);
        v.z = bf2f(ua.z) + bf2f(ub.z);
        v.w = bf2f(ua.w) + bf2f(ub.w);
        o[i] = v;
    }
}

// ---------------------------------------------------------------------------
// Workspace layout (peak 205.7 MB)
// ---------------------------------------------------------------------------
extern "C" void kernel_launch(void* const* d_in, const int* in_sizes, int n_in,
                              void* d_out, int out_size, void* d_ws, size_t ws_size,
                              hipStream_t stream) {
    const float* x        = (const float*)d_in[0];
    const int*   topk_idx = (const int*)d_in[1];
    const float* topk_scr = (const float*)d_in[2];
    const float* Wg       = (const float*)d_in[3];
    const float* Wu       = (const float*)d_in[4];
    const float* Wd       = (const float*)d_in[5];
    float* y = (float*)d_out;

    char* ws = (char*)d_ws;
    const size_t wbytes = (size_t)NUM_EXP * D_MODEL * H_EXP * 2;  // 46,137,344
    size_t off = 0;
    unsigned short* buf0 = (unsigned short*)(ws + off); off += wbytes;  // Wgt -> Wdt
    unsigned short* Wut  = (unsigned short*)(ws + off); off += wbytes;
    unsigned short* hb   = (unsigned short*)(ws + off); off += wbytes;
    unsigned short* xs   = (unsigned short*)(ws + off); off += (size_t)N_SLOTS * D_MODEL * 2;
    int*   src_token = (int*)(ws + off);   off += (size_t)N_SLOTS * 4;
    float* src_score = (float*)(ws + off); off += (size_t)N_SLOTS * 4;
    int*   pos_slot  = (int*)(ws + off);   off += (size_t)N_SLOTS * 4;
    unsigned short* Wgt  = buf0;
    unsigned short* Wdt  = buf0;  // reused after gemm12 (stream-serialized)
    unsigned short* dbuf = xs;    // xs dead after gemm12

    route_kernel<<<NUM_EXP, 256, 0, stream>>>(topk_idx, topk_scr, src_token, src_score, pos_slot);
    transpose_cast_kernel<<<dim3(H_EXP / 32, D_MODEL / 32, NUM_EXP), 256, 0, stream>>>(Wg, Wgt, D_MODEL, H_EXP);
    transpose_cast_kernel<<<dim3(H_EXP / 32, D_MODEL / 32, NUM_EXP), 256, 0, stream>>>(Wu, Wut, D_MODEL, H_EXP);
    gather_cast_kernel<<<N_SLOTS, 256, 0, stream>>>(x, src_token, xs);
    gemm12_kernel<<<dim3(CAP / 256, H_EXP / 128, NUM_EXP), 512, 0, stream>>>(xs, Wgt, Wut, hb);
    transpose_cast_kernel<<<dim3(D_MODEL / 32, H_EXP / 32, NUM_EXP), 256, 0, stream>>>(Wd, Wdt, H_EXP, D_MODEL);
    gemm3_kernel<<<dim3(CAP / 256, D_MODEL / 256, NUM_EXP), 512, 0, stream>>>(hb, Wdt, src_score, dbuf);
    combine_kernel<<<NUM_TOKENS, 256, 0, stream>>>(dbuf, pos_slot, y);
}